// Round 5
// baseline (202.262 us; speedup 1.0000x reference)
//
#include <hip/hip_runtime.h>
#include <hip/hip_bf16.h>

// KPConv v5 — hardened fused (R4 diverged post-timing; suspected cross-wave
// staging race + float4.w index smuggling; both removed here):
//   prep:  x -> xb bf16  AND  weights -> Wt2[o][c*16+k] bf16 (c-major K=1024,
//          k=15 slot zeroed)   [unchanged, proven R3/R4]
//   fused: per block of 16 points (4 waves x 4 points, wave-local staging):
//     phase1: wfT[p][c*16+k] = sum_h w(h,k)*x(h,c) via per-point 16x16x32 MFMA
//             (A = w in-register, B = scalar-u16 gathered xb), D -> LDS wfT
//     phase2: out[16,128] = wfT[16,1024] x Wt2^T MFMA GEMM (B from global,
//             L2-resident 256 KB) + bias
//   wf never touches HBM (kills 100 MB write + 96 MB read + L3 eviction of xb).

#define NPTS   50000
#define HNB    32
#define KPTS   15
#define CING   64
#define COUTG  128
#define KDIM2  1024
#define MSUP   50000
#define INV_EXT 13.888889f

#define PTS_BLK 16
#define PITCH   1040   // wfT row pitch (elems): 2080 B, 16B-aligned rows

typedef __attribute__((ext_vector_type(8))) short bf16x8;
typedef __attribute__((ext_vector_type(4))) float f32x4;

static __device__ __forceinline__ unsigned short f2bf(float f) {
    unsigned int u = __float_as_uint(f);
    u += 0x7FFFu + ((u >> 16) & 1u);   // round-to-nearest-even
    return (unsigned short)(u >> 16);
}

// ---------------- prep: x->bf16 (blocks 0..1562) + Wt2 (blocks 1563..2074) ----
#define XBLKS 1563
__global__ __launch_bounds__(256) void kpconv_prep(
    const float* __restrict__ x, const float* __restrict__ wgt,
    unsigned short* __restrict__ xb, unsigned short* __restrict__ Wt2)
{
    int b = blockIdx.x;
    if (b < XBLKS) {
        int i = (b * 256 + threadIdx.x) * 8;
        if (i < MSUP * CING) {
            float4 a = *(const float4*)(x + i);
            float4 c = *(const float4*)(x + i + 4);
            unsigned short o[8];
            o[0]=f2bf(a.x); o[1]=f2bf(a.y); o[2]=f2bf(a.z); o[3]=f2bf(a.w);
            o[4]=f2bf(c.x); o[5]=f2bf(c.y); o[6]=f2bf(c.z); o[7]=f2bf(c.w);
            uint4 p;
            p.x = o[0] | (o[1]<<16); p.y = o[2] | (o[3]<<16);
            p.z = o[4] | (o[5]<<16); p.w = o[6] | (o[7]<<16);
            *(uint4*)(xb + i) = p;
        }
    } else {
        int e = (b - XBLKS) * 256 + threadIdx.x;   // 0..131071
        int o = e >> 10, j = e & 1023;
        int c = j >> 4, k = j & 15;
        Wt2[(size_t)o * KDIM2 + j] =
            (k < KPTS) ? f2bf(wgt[((size_t)k * CING + c) * COUTG + o]) : (unsigned short)0;
    }
}

// ---------------- fused agg + gemm ----------------
// Grid 3125 blocks x 256 threads (4 waves). 16 points/block, 4 per wave.
__global__ __launch_bounds__(256) void kpconv_fused(
    const float* __restrict__ q_pts, const float* __restrict__ s_pts,
    const int* __restrict__ inds, const unsigned short* __restrict__ xb,
    const float* __restrict__ kpts, const unsigned short* __restrict__ Wt2,
    const float* __restrict__ bias, float* __restrict__ out)
{
    __shared__ float nbx[PTS_BLK][HNB];                // 2048 B
    __shared__ float nby[PTS_BLK][HNB];                // 2048 B
    __shared__ float nbz[PTS_BLK][HNB];                // 2048 B
    __shared__ int   sidx[PTS_BLK][HNB];               // 2048 B
    __shared__ unsigned short wfT[PTS_BLK * PITCH];    // 33280 B

    const int tid  = threadIdx.x;
    const int wave = tid >> 6;
    const int lane = tid & 63;
    const int l15  = lane & 15;
    const int quad = lane >> 4;
    const int n0   = blockIdx.x * PTS_BLK;

    // ---- wave-local staging: each wave stages its OWN 4 points ----
    // (lockstep within the wave -> no inter-wave LDS dependency at all)
#pragma unroll
    for (int pq = 0; pq < 2; ++pq) {
        const int p = wave * 4 + pq * 2 + (lane >> 5);
        const int h = lane & 31;
        const int n = n0 + p;
        const int m = inds[n * HNB + h];
        sidx[p][h] = m;
        nbx[p][h] = s_pts[(size_t)m * 3 + 0] - q_pts[n * 3 + 0];
        nby[p][h] = s_pts[(size_t)m * 3 + 1] - q_pts[n * 3 + 1];
        nbz[p][h] = s_pts[(size_t)m * 3 + 2] - q_pts[n * 3 + 2];
    }
    __syncthreads();   // belt-and-suspenders (wave-local data)

    const bool kvalid = (l15 < KPTS);
    const int  kidx   = kvalid ? l15 : 0;
    const float kx = kpts[kidx * 3 + 0];
    const float ky = kpts[kidx * 3 + 1];
    const float kz = kpts[kidx * 3 + 2];

    // ---- phase 1: per-point MFMA, D -> wfT (wave writes its own 4 rows) ----
#pragma unroll
    for (int pp = 0; pp < 4; ++pp) {
        const int p = wave * 4 + pp;

        int mrow[8];
#pragma unroll
        for (int j = 0; j < 8; ++j) mrow[j] = sidx[p][quad * 8 + j];

        // 32 scalar u16 gathers, issued together (B-frags in MFMA layout)
        unsigned short bv[4][8];
#pragma unroll
        for (int nt = 0; nt < 4; ++nt) {
            const int c = nt * 16 + l15;
#pragma unroll
            for (int j = 0; j < 8; ++j)
                bv[nt][j] = xb[((size_t)mrow[j] << 6) + c];
        }

        // A-frag (w) — VALU work overlaps gather latency
        bf16x8 af;
#pragma unroll
        for (int j = 0; j < 8; ++j) {
            const int h = quad * 8 + j;
            float dx = nbx[p][h] - kx;
            float dy = nby[p][h] - ky;
            float dz = nbz[p][h] - kz;
            float d  = sqrtf(dx * dx + dy * dy + dz * dz);
            float w  = kvalid ? fmaxf(0.f, 1.f - d * INV_EXT) : 0.f;
            af[j] = (short)f2bf(w);
        }

#pragma unroll
        for (int nt = 0; nt < 4; ++nt) {
            bf16x8 bfr;
#pragma unroll
            for (int j = 0; j < 8; ++j) bfr[j] = (short)bv[nt][j];
            f32x4 acc = (f32x4){0.f, 0.f, 0.f, 0.f};
            acc = __builtin_amdgcn_mfma_f32_16x16x32_bf16(af, bfr, acc, 0, 0, 0);
            // D[row=k=quad*4+r][col=c=nt*16+l15] -> wfT[p][c*16+k], 8 B store
            uint2 pk;
            pk.x = f2bf(acc[0]) | ((unsigned int)f2bf(acc[1]) << 16);
            pk.y = f2bf(acc[2]) | ((unsigned int)f2bf(acc[3]) << 16);
            *(uint2*)&wfT[p * PITCH + (nt * 16 + l15) * 16 + quad * 4] = pk;
        }
    }
    __syncthreads();   // all 16 wfT rows visible to all waves

    // ---- phase 2: out[16,128] = wfT[16,1024] x Wt2^T ----
    f32x4 acc2[2];
    acc2[0] = (f32x4){0.f, 0.f, 0.f, 0.f};
    acc2[1] = (f32x4){0.f, 0.f, 0.f, 0.f};

    const int col0 = wave * 32 + l15;
    const unsigned short* bp0 = Wt2 + (size_t)col0 * KDIM2 + quad * 8;
    const unsigned short* bp1 = bp0 + 16 * KDIM2;

#pragma unroll 4
    for (int ks = 0; ks < 32; ++ks) {
        bf16x8 afr = *(bf16x8*)&wfT[l15 * PITCH + ks * 32 + quad * 8];
        bf16x8 b0  = *(const bf16x8*)(bp0 + ks * 32);
        bf16x8 b1  = *(const bf16x8*)(bp1 + ks * 32);
        acc2[0] = __builtin_amdgcn_mfma_f32_16x16x32_bf16(afr, b0, acc2[0], 0, 0, 0);
        acc2[1] = __builtin_amdgcn_mfma_f32_16x16x32_bf16(afr, b1, acc2[1], 0, 0, 0);
    }

#pragma unroll
    for (int nf = 0; nf < 2; ++nf) {
        const int col = col0 + nf * 16;
        const float bvs = bias[col];
#pragma unroll
        for (int r = 0; r < 4; ++r) {
            const int row = n0 + quad * 4 + r;       // always < 50000 (exact grid)
            out[(size_t)row * COUTG + col] = acc2[nf][r] + bvs;
        }
    }
}

extern "C" void kernel_launch(void* const* d_in, const int* in_sizes, int n_in,
                              void* d_out, int out_size, void* d_ws, size_t ws_size,
                              hipStream_t stream) {
    const float* q_pts = (const float*)d_in[0];
    const float* s_pts = (const float*)d_in[1];
    const int*   inds  = (const int*)d_in[2];
    const float* x     = (const float*)d_in[3];
    const float* kpts  = (const float*)d_in[4];
    const float* wgt   = (const float*)d_in[5];
    const float* bias  = (const float*)d_in[6];
    float* out = (float*)d_out;

    // ws: xb [50000*64] bf16 | Wt2 [128*1024] bf16   (6.7 MB total)
    unsigned short* xb  = (unsigned short*)d_ws;
    unsigned short* Wt2 = xb + (size_t)MSUP * CING;

    kpconv_prep<<<XBLKS + 512, 256, 0, stream>>>(x, wgt, xb, Wt2);
    kpconv_fused<<<NPTS / PTS_BLK, 256, 0, stream>>>(q_pts, s_pts, inds, xb,
                                                     kpts, Wt2, bias, out);
}

// Round 6
// 171.101 us; speedup vs baseline: 1.1821x; 1.1821x over previous
//
#include <hip/hip_runtime.h>
#include <hip/hip_bf16.h>

// KPConv v6 — fused, restructured:
//   prep:  x -> xb2 bf16 in PERMUTED layout: xb2[m][c'] with c'=(c&15)*4+(c>>4)
//          so one dwordx2 per (h, l15) yields all 4 nt-values (8 loads/point
//          instead of 32 scalar u16); plus Wt2[o][c*16+k] bf16 (k=15 zeroed).
//   fused: 512 thr (8 waves), 32 points/block (4/wave), grid 1563:
//     phase1: per-point 16x16x32 MFMA (A=w in-register via shuffle-staged
//             coords, B=coalesced dwordx2 gathers + register extracts),
//             D -> LDS wfT[32][1032]  (only LDS use: 64.5 KB -> 2 blocks/CU)
//     phase2: out[32,128] = wfT x Wt2^T; each wave a 16-col strip, 2 MFMA/ks.
//             Per-block Wt2 read 256 KB for 32 pts (half of v5 per point).

#define NPTS   50000
#define HNB    32
#define KPTS   15
#define CING   64
#define COUTG  128
#define KDIM2  1024
#define MSUP   50000
#define INV_EXT 13.888889f

#define PTS_BLK 32
#define PITCH   1032   // elems/row = 2064 B; stride 516 dwords = 4*odd -> b128 conflict-free

typedef __attribute__((ext_vector_type(8))) short bf16x8;
typedef __attribute__((ext_vector_type(4))) float f32x4;

static __device__ __forceinline__ unsigned short f2bf(float f) {
    unsigned int u = __float_as_uint(f);
    u += 0x7FFFu + ((u >> 16) & 1u);   // round-to-nearest-even
    return (unsigned short)(u >> 16);
}

// ---------------- prep ----------------
// blocks 0..1562: xb2 (output-centric: thread computes 8 consecutive c' slots)
// blocks 1563..2074: Wt2
#define XBLKS 1563
__global__ __launch_bounds__(256) void kpconv_prep(
    const float* __restrict__ x, const float* __restrict__ wgt,
    unsigned short* __restrict__ xb2, unsigned short* __restrict__ Wt2)
{
    int b = blockIdx.x;
    if (b < XBLKS) {
        int e = b * 256 + threadIdx.x;            // 8-elem output group
        if (e < MSUP * CING / 8) {
            int m  = e >> 3;
            int g8 = (e & 7) * 8;                  // c' base
            unsigned short o[8];
#pragma unroll
            for (int i = 0; i < 8; ++i) {
                // c' = g8+i ;  c = (c'&3)*16 + (c'>>2) = (i&3)*16 + 2*(e&7) + (i>>2)
                int c = ((i & 3) << 4) + ((e & 7) << 1) + (i >> 2);
                o[i] = f2bf(x[(size_t)m * CING + c]);
            }
            uint4 p;
            p.x = o[0] | ((unsigned)o[1] << 16);
            p.y = o[2] | ((unsigned)o[3] << 16);
            p.z = o[4] | ((unsigned)o[5] << 16);
            p.w = o[6] | ((unsigned)o[7] << 16);
            *(uint4*)(xb2 + (size_t)m * CING + g8) = p;
        }
    } else {
        int e = (b - XBLKS) * 256 + threadIdx.x;   // 0..131071
        int o = e >> 10, j = e & 1023;
        int c = j >> 4, k = j & 15;
        Wt2[(size_t)o * KDIM2 + j] =
            (k < KPTS) ? f2bf(wgt[((size_t)k * CING + c) * COUTG + o]) : (unsigned short)0;
    }
}

// ---------------- fused ----------------
// Grid 1563 x 512 threads (8 waves). 32 points/block, 4 per wave.
__global__ __launch_bounds__(512, 4) void kpconv_fused(
    const float* __restrict__ q_pts, const float* __restrict__ s_pts,
    const int* __restrict__ inds, const unsigned short* __restrict__ xb2,
    const float* __restrict__ kpts, const unsigned short* __restrict__ Wt2,
    const float* __restrict__ bias, float* __restrict__ out)
{
    __shared__ unsigned short wfT[PTS_BLK * PITCH];   // 66048 B (only LDS)

    const int tid  = threadIdx.x;
    const int wave = tid >> 6;        // 0..7
    const int lane = tid & 63;
    const int l15  = lane & 15;
    const int quad = lane >> 4;
    const int n0   = blockIdx.x * PTS_BLK;
    const int p0   = wave * 4;        // wave's first block-local point

    // ---- register staging: this wave's 4 points, 2 per half-wave ----
    const int hh = lane & 31;
    int nA = n0 + p0 + (lane >> 5);        // points p0, p0+1
    int nB = nA + 2;                        // points p0+2, p0+3
    if (nA >= NPTS) nA = NPTS - 1;
    if (nB >= NPTS) nB = NPTS - 1;
    const int idxA = inds[nA * HNB + hh];
    const int idxB = inds[nB * HNB + hh];
    const float dxA = s_pts[(size_t)idxA * 3 + 0] - q_pts[nA * 3 + 0];
    const float dyA = s_pts[(size_t)idxA * 3 + 1] - q_pts[nA * 3 + 1];
    const float dzA = s_pts[(size_t)idxA * 3 + 2] - q_pts[nA * 3 + 2];
    const float dxB = s_pts[(size_t)idxB * 3 + 0] - q_pts[nB * 3 + 0];
    const float dyB = s_pts[(size_t)idxB * 3 + 1] - q_pts[nB * 3 + 1];
    const float dzB = s_pts[(size_t)idxB * 3 + 2] - q_pts[nB * 3 + 2];

    const bool kvalid = (l15 < KPTS);
    const int  kidx   = kvalid ? l15 : 0;
    const float kx = kpts[kidx * 3 + 0];
    const float ky = kpts[kidx * 3 + 1];
    const float kz = kpts[kidx * 3 + 2];

    // ---- phase 1: 4 points, each one 16x16x32 MFMA ----
#pragma unroll
    for (int pp = 0; pp < 4; ++pp) {
        const int p = p0 + pp;
        const int sbase = (pp & 1) << 5;   // source half-wave

        // neighbor indices for h = quad*8+j via shuffle
        int mrow[8];
#pragma unroll
        for (int j = 0; j < 8; ++j) {
            int src = sbase + quad * 8 + j;
            mrow[j] = (pp < 2) ? __shfl(idxA, src) : __shfl(idxB, src);
        }

        // coalesced gathers: 8 x dwordx2; quad's 16 lanes cover one 128B row
        uint2 g[8];
#pragma unroll
        for (int j = 0; j < 8; ++j)
            g[j] = *(const uint2*)(xb2 + ((size_t)mrow[j] << 6) + (l15 << 2));

        // A-frag (w) from shuffled coords — overlaps gather latency
        bf16x8 af;
#pragma unroll
        for (int j = 0; j < 8; ++j) {
            int src = sbase + quad * 8 + j;
            float hx = (pp < 2) ? __shfl(dxA, src) : __shfl(dxB, src);
            float hy = (pp < 2) ? __shfl(dyA, src) : __shfl(dyB, src);
            float hz = (pp < 2) ? __shfl(dzA, src) : __shfl(dzB, src);
            float ddx = hx - kx, ddy = hy - ky, ddz = hz - kz;
            float d = sqrtf(ddx * ddx + ddy * ddy + ddz * ddz);
            float w = kvalid ? fmaxf(0.f, 1.f - d * INV_EXT) : 0.f;
            af[j] = (short)f2bf(w);
        }

        // 4 MFMAs, B-frags via register extracts (nt-th u16 of each g[j])
#pragma unroll
        for (int nt = 0; nt < 4; ++nt) {
            bf16x8 bfr;
#pragma unroll
            for (int j = 0; j < 8; ++j) {
                unsigned int wsel = (nt < 2) ? g[j].x : g[j].y;
                bfr[j] = (short)(unsigned short)(wsel >> (16 * (nt & 1)));
            }
            f32x4 acc = (f32x4){0.f, 0.f, 0.f, 0.f};
            acc = __builtin_amdgcn_mfma_f32_16x16x32_bf16(af, bfr, acc, 0, 0, 0);
            // D[k=quad*4+r][c=nt*16+l15] -> wfT[p][c*16+k]  (8 B store)
            uint2 pk;
            pk.x = f2bf(acc[0]) | ((unsigned int)f2bf(acc[1]) << 16);
            pk.y = f2bf(acc[2]) | ((unsigned int)f2bf(acc[3]) << 16);
            *(uint2*)&wfT[p * PITCH + (nt * 16 + l15) * 16 + quad * 4] = pk;
        }
    }
    __syncthreads();

    // ---- phase 2: out[32,128] = wfT[32,1024] x Wt2^T; wave = 16-col strip ----
    f32x4 acc0 = (f32x4){0.f, 0.f, 0.f, 0.f};
    f32x4 acc1 = (f32x4){0.f, 0.f, 0.f, 0.f};

    const int col = wave * 16 + l15;
    const unsigned short* bp = Wt2 + (size_t)col * KDIM2 + quad * 8;
    const unsigned short* a0 = wfT + l15 * PITCH + quad * 8;
    const unsigned short* a1 = a0 + 16 * PITCH;

#pragma unroll 4
    for (int ks = 0; ks < 32; ++ks) {
        bf16x8 b   = *(const bf16x8*)(bp + ks * 32);
        bf16x8 fa0 = *(const bf16x8*)(a0 + ks * 32);
        bf16x8 fa1 = *(const bf16x8*)(a1 + ks * 32);
        acc0 = __builtin_amdgcn_mfma_f32_16x16x32_bf16(fa0, b, acc0, 0, 0, 0);
        acc1 = __builtin_amdgcn_mfma_f32_16x16x32_bf16(fa1, b, acc1, 0, 0, 0);
    }

    const float bv = bias[col];
#pragma unroll
    for (int r = 0; r < 4; ++r) {
        int r0 = n0 + quad * 4 + r;
        int r1 = r0 + 16;
        if (r0 < NPTS) out[(size_t)r0 * COUTG + col] = acc0[r] + bv;
        if (r1 < NPTS) out[(size_t)r1 * COUTG + col] = acc1[r] + bv;
    }
}

extern "C" void kernel_launch(void* const* d_in, const int* in_sizes, int n_in,
                              void* d_out, int out_size, void* d_ws, size_t ws_size,
                              hipStream_t stream) {
    const float* q_pts = (const float*)d_in[0];
    const float* s_pts = (const float*)d_in[1];
    const int*   inds  = (const int*)d_in[2];
    const float* x     = (const float*)d_in[3];
    const float* kpts  = (const float*)d_in[4];
    const float* wgt   = (const float*)d_in[5];
    const float* bias  = (const float*)d_in[6];
    float* out = (float*)d_out;

    // ws: xb2 [50000*64] bf16 | Wt2 [128*1024] bf16   (6.7 MB total)
    unsigned short* xb2 = (unsigned short*)d_ws;
    unsigned short* Wt2 = xb2 + (size_t)MSUP * CING;

    kpconv_prep<<<XBLKS + 512, 256, 0, stream>>>(x, wgt, xb2, Wt2);
    kpconv_fused<<<(NPTS + PTS_BLK - 1) / PTS_BLK, 512, 0, stream>>>(
        q_pts, s_pts, inds, xb2, kpts, Wt2, bias, out);
}

// Round 7
// 170.271 us; speedup vs baseline: 1.1879x; 1.0049x over previous
//
#include <hip/hip_runtime.h>
#include <hip/hip_bf16.h>

// KPConv v7 — fused, phase-1 single-latency-window:
//   prep:  x -> xb2 bf16 permuted (c'=(c&15)*4+(c>>4)) + Wt2[o][c*16+k] bf16.
//   fused: 512 thr (8 waves), 32 points/block (4/wave), grid 1563:
//     phase1: ALL 32 gathers (4 pts x 8 dwordx2) issued in ONE window, then
//             A-frags (w) computed under vmcnt, then 16 MFMAs + wfT stores.
//     phase2: out[32,128] = wfT x Wt2^T, wave = 16-col strip, unroll 8.
//   R6 evidence: VGPR=52 showed per-pp serialized gather windows (4 x ~500cyc);
//   bank-conflict 5.6e6 = 512 b128/block x 7 = structural full-wave b128 cost.

#define NPTS   50000
#define HNB    32
#define KPTS   15
#define CING   64
#define COUTG  128
#define KDIM2  1024
#define MSUP   50000
#define INV_EXT 13.888889f

#define PTS_BLK 32
#define PITCH   1032   // elems/row; stride 516 dwords -> phase-1 b64 stores conflict-free

typedef __attribute__((ext_vector_type(8))) short bf16x8;
typedef __attribute__((ext_vector_type(4))) float f32x4;

static __device__ __forceinline__ unsigned short f2bf(float f) {
    unsigned int u = __float_as_uint(f);
    u += 0x7FFFu + ((u >> 16) & 1u);   // round-to-nearest-even
    return (unsigned short)(u >> 16);
}

// ---------------- prep (unchanged, proven R6) ----------------
#define XBLKS 1563
__global__ __launch_bounds__(256) void kpconv_prep(
    const float* __restrict__ x, const float* __restrict__ wgt,
    unsigned short* __restrict__ xb2, unsigned short* __restrict__ Wt2)
{
    int b = blockIdx.x;
    if (b < XBLKS) {
        int e = b * 256 + threadIdx.x;
        if (e < MSUP * CING / 8) {
            int m  = e >> 3;
            int g8 = (e & 7) * 8;
            unsigned short o[8];
#pragma unroll
            for (int i = 0; i < 8; ++i) {
                int c = ((i & 3) << 4) + ((e & 7) << 1) + (i >> 2);
                o[i] = f2bf(x[(size_t)m * CING + c]);
            }
            uint4 p;
            p.x = o[0] | ((unsigned)o[1] << 16);
            p.y = o[2] | ((unsigned)o[3] << 16);
            p.z = o[4] | ((unsigned)o[5] << 16);
            p.w = o[6] | ((unsigned)o[7] << 16);
            *(uint4*)(xb2 + (size_t)m * CING + g8) = p;
        }
    } else {
        int e = (b - XBLKS) * 256 + threadIdx.x;
        int o = e >> 10, j = e & 1023;
        int c = j >> 4, k = j & 15;
        Wt2[(size_t)o * KDIM2 + j] =
            (k < KPTS) ? f2bf(wgt[((size_t)k * CING + c) * COUTG + o]) : (unsigned short)0;
    }
}

// ---------------- fused ----------------
__global__ __launch_bounds__(512, 4) void kpconv_fused(
    const float* __restrict__ q_pts, const float* __restrict__ s_pts,
    const int* __restrict__ inds, const unsigned short* __restrict__ xb2,
    const float* __restrict__ kpts, const unsigned short* __restrict__ Wt2,
    const float* __restrict__ bias, float* __restrict__ out)
{
    __shared__ unsigned short wfT[PTS_BLK * PITCH];   // 66048 B

    const int tid  = threadIdx.x;
    const int wave = tid >> 6;
    const int lane = tid & 63;
    const int l15  = lane & 15;
    const int quad = lane >> 4;
    const int n0   = blockIdx.x * PTS_BLK;
    const int p0   = wave * 4;

    // ---- register staging: this wave's 4 points, 2 per half-wave ----
    const int hh = lane & 31;
    int nA = n0 + p0 + (lane >> 5);
    int nB = nA + 2;
    if (nA >= NPTS) nA = NPTS - 1;
    if (nB >= NPTS) nB = NPTS - 1;
    const int idxA = inds[nA * HNB + hh];
    const int idxB = inds[nB * HNB + hh];
    const float dxA = s_pts[(size_t)idxA * 3 + 0] - q_pts[nA * 3 + 0];
    const float dyA = s_pts[(size_t)idxA * 3 + 1] - q_pts[nA * 3 + 1];
    const float dzA = s_pts[(size_t)idxA * 3 + 2] - q_pts[nA * 3 + 2];
    const float dxB = s_pts[(size_t)idxB * 3 + 0] - q_pts[nB * 3 + 0];
    const float dyB = s_pts[(size_t)idxB * 3 + 1] - q_pts[nB * 3 + 1];
    const float dzB = s_pts[(size_t)idxB * 3 + 2] - q_pts[nB * 3 + 2];

    const bool kvalid = (l15 < KPTS);
    const int  kidx   = kvalid ? l15 : 0;
    const float kx = kpts[kidx * 3 + 0];
    const float ky = kpts[kidx * 3 + 1];
    const float kz = kpts[kidx * 3 + 2];

    // ---- phase 1a: issue ALL 32 gathers in one latency window ----
    uint2 g[4][8];
#pragma unroll
    for (int pp = 0; pp < 4; ++pp) {
        const int sbase = (pp & 1) << 5;
#pragma unroll
        for (int j = 0; j < 8; ++j) {
            const int src = sbase + quad * 8 + j;
            const int m = (pp < 2) ? __shfl(idxA, src) : __shfl(idxB, src);
            g[pp][j] = *(const uint2*)(xb2 + ((size_t)m << 6) + (l15 << 2));
        }
    }

    // ---- phase 1b: A-frags for all 4 points (VALU under vmcnt) ----
    bf16x8 af[4];
#pragma unroll
    for (int pp = 0; pp < 4; ++pp) {
        const int sbase = (pp & 1) << 5;
#pragma unroll
        for (int j = 0; j < 8; ++j) {
            const int src = sbase + quad * 8 + j;
            float hx = (pp < 2) ? __shfl(dxA, src) : __shfl(dxB, src);
            float hy = (pp < 2) ? __shfl(dyA, src) : __shfl(dyB, src);
            float hz = (pp < 2) ? __shfl(dzA, src) : __shfl(dzB, src);
            float ddx = hx - kx, ddy = hy - ky, ddz = hz - kz;
            float d = sqrtf(ddx * ddx + ddy * ddy + ddz * ddz);
            float w = kvalid ? fmaxf(0.f, 1.f - d * INV_EXT) : 0.f;
            af[pp][j] = (short)f2bf(w);
        }
    }

    // ---- phase 1c: 16 MFMAs + wfT stores (consume loads oldest-first) ----
#pragma unroll
    for (int pp = 0; pp < 4; ++pp) {
        const int p = p0 + pp;
#pragma unroll
        for (int nt = 0; nt < 4; ++nt) {
            bf16x8 bfr;
#pragma unroll
            for (int j = 0; j < 8; ++j) {
                unsigned int wsel = (nt < 2) ? g[pp][j].x : g[pp][j].y;
                bfr[j] = (short)(unsigned short)(wsel >> (16 * (nt & 1)));
            }
            f32x4 acc = (f32x4){0.f, 0.f, 0.f, 0.f};
            acc = __builtin_amdgcn_mfma_f32_16x16x32_bf16(af[pp], bfr, acc, 0, 0, 0);
            uint2 pk;
            pk.x = f2bf(acc[0]) | ((unsigned int)f2bf(acc[1]) << 16);
            pk.y = f2bf(acc[2]) | ((unsigned int)f2bf(acc[3]) << 16);
            *(uint2*)&wfT[p * PITCH + (nt * 16 + l15) * 16 + quad * 4] = pk;
        }
    }
    __syncthreads();

    // ---- phase 2: out[32,128] = wfT[32,1024] x Wt2^T; wave = 16-col strip ----
    f32x4 acc0 = (f32x4){0.f, 0.f, 0.f, 0.f};
    f32x4 acc1 = (f32x4){0.f, 0.f, 0.f, 0.f};

    const int col = wave * 16 + l15;
    const unsigned short* bp = Wt2 + (size_t)col * KDIM2 + quad * 8;
    const unsigned short* a0 = wfT + l15 * PITCH + quad * 8;
    const unsigned short* a1 = a0 + 16 * PITCH;

#pragma unroll 8
    for (int ks = 0; ks < 32; ++ks) {
        bf16x8 b   = *(const bf16x8*)(bp + ks * 32);
        bf16x8 fa0 = *(const bf16x8*)(a0 + ks * 32);
        bf16x8 fa1 = *(const bf16x8*)(a1 + ks * 32);
        acc0 = __builtin_amdgcn_mfma_f32_16x16x32_bf16(fa0, b, acc0, 0, 0, 0);
        acc1 = __builtin_amdgcn_mfma_f32_16x16x32_bf16(fa1, b, acc1, 0, 0, 0);
    }

    const float bv = bias[col];
#pragma unroll
    for (int r = 0; r < 4; ++r) {
        int r0 = n0 + quad * 4 + r;
        int r1 = r0 + 16;
        if (r0 < NPTS) out[(size_t)r0 * COUTG + col] = acc0[r] + bv;
        if (r1 < NPTS) out[(size_t)r1 * COUTG + col] = acc1[r] + bv;
    }
}

extern "C" void kernel_launch(void* const* d_in, const int* in_sizes, int n_in,
                              void* d_out, int out_size, void* d_ws, size_t ws_size,
                              hipStream_t stream) {
    const float* q_pts = (const float*)d_in[0];
    const float* s_pts = (const float*)d_in[1];
    const int*   inds  = (const int*)d_in[2];
    const float* x     = (const float*)d_in[3];
    const float* kpts  = (const float*)d_in[4];
    const float* wgt   = (const float*)d_in[5];
    const float* bias  = (const float*)d_in[6];
    float* out = (float*)d_out;

    unsigned short* xb2 = (unsigned short*)d_ws;
    unsigned short* Wt2 = xb2 + (size_t)MSUP * CING;

    kpconv_prep<<<XBLKS + 512, 256, 0, stream>>>(x, wgt, xb2, Wt2);
    kpconv_fused<<<(NPTS + PTS_BLK - 1) / PTS_BLK, 512, 0, stream>>>(
        q_pts, s_pts, inds, xb2, kpts, Wt2, bias, out);
}